// Round 1
// baseline (289.716 us; speedup 1.0000x reference)
//
#include <hip/hip_runtime.h>

#define NE 8
#define CAP 1024
#define HD 1024
#define ID 1408
#define TT 2048

typedef __attribute__((ext_vector_type(8))) short bf16x8;
typedef __attribute__((ext_vector_type(4))) float f32x4;
typedef unsigned short u16;
typedef unsigned int u32;

__device__ __forceinline__ u16 f2bf(float f) {
  u32 u = __float_as_uint(f);
  u = (u + 0x7fffu + ((u >> 16) & 1u)) >> 16;
  return (u16)u;
}
__device__ __forceinline__ float bf2f(u16 b) {
  return __uint_as_float(((u32)b) << 16);
}

__device__ __forceinline__ void async_cp16(const void* g, void* l) {
  __builtin_amdgcn_global_load_lds(
      (const __attribute__((address_space(1))) u32*)g,
      (__attribute__((address_space(3))) u32*)l, 16, 0, 0);
}

// ---------------- fp32 -> bf16 convert ----------------
__global__ void cvt_kernel(const float4* __restrict__ src, ushort4* __restrict__ dst, int n4) {
  int i = blockIdx.x * 256 + threadIdx.x;
  if (i >= n4) return;
  float4 v = src[i];
  ushort4 o;
  o.x = f2bf(v.x); o.y = f2bf(v.y); o.z = f2bf(v.z); o.w = f2bf(v.w);
  dst[i] = o;
}

// ---------------- routing: exact flat-order cumsum positions ----------------
__global__ void route_kernel(const int* __restrict__ ids, int* __restrict__ rowmap,
                             int* __restrict__ flatpos, int* __restrict__ counts) {
  __shared__ int ids_s[TT * 2];
  __shared__ int lc[256][NE];
  int tid = threadIdx.x;
  for (int i = tid; i < TT * 2; i += 256) ids_s[i] = ids[i];
#pragma unroll
  for (int e = 0; e < NE; ++e) lc[tid][e] = 0;
  __syncthreads();
  int base = tid * 16;
#pragma unroll
  for (int j = 0; j < 16; ++j) lc[tid][ids_s[base + j]]++;
  __syncthreads();
  if (tid < NE) {
    int run = 0;
    for (int t = 0; t < 256; ++t) { int v = lc[t][tid]; lc[t][tid] = run; run += v; }
    counts[tid] = run < CAP ? run : CAP;
  }
  __syncthreads();
#pragma unroll
  for (int j = 0; j < 16; ++j) {
    int f = base + j;
    int e = ids_s[f];
    int p = lc[tid][e]++;
    if (p < CAP) { rowmap[e * CAP + p] = f; flatpos[f] = p; }
    else flatpos[f] = -1;
  }
}

// ---------------- bf16 BT GEMM: C[m,n] = sum_k A[m,k]*B[n,k] ----------------
// m97 structure: 128x128 tile, BK=64, 4 waves (2x2 of 64x64), 16x16x32 MFMA,
// global_load_lds width=16, XOR chunk swizzle (slot ch holds global chunk ch^(row&7)).
template <bool GATHER>
__global__ __launch_bounds__(256) void gemm_bt(
    const u16* __restrict__ A, const u16* __restrict__ B, u16* __restrict__ C,
    const int* __restrict__ rowmap, const int* __restrict__ counts,
    int KE, int Astride, long long Bexp, int Cstride) {
  int e = blockIdx.z;
  int count = counts[e];
  int m0 = blockIdx.y * 128;
  if (m0 >= count) return;
  int n0 = blockIdx.x * 128;
  int tid = threadIdx.x;
  int lane = tid & 63, wid = tid >> 6;
  int wm = wid >> 1, wn = wid & 1;
  int q = lane >> 4, lm = lane & 15;

  __shared__ __align__(16) char smA[128 * 128];
  __shared__ __align__(16) char smB[128 * 128];

  int rloc = tid >> 3;
  int chs = ((tid & 7) ^ (rloc & 7)) * 8;  // swizzled element offset within 64-elem k-tile
  const u16* aP[4];
  const u16* bP[4];
#pragma unroll
  for (int i = 0; i < 4; ++i) {
    int row = rloc + 32 * i;
    if (GATHER) {
      int gr = m0 + row;
      int f = (gr < count) ? rowmap[e * CAP + gr] : 0;
      aP[i] = A + (size_t)(f >> 1) * Astride + chs;  // token = f/2 (K_top=2)
    } else {
      aP[i] = A + ((size_t)e * CAP + m0 + row) * Astride + chs;
    }
    bP[i] = B + (size_t)e * Bexp + (size_t)(n0 + row) * KE + chs;
  }

  f32x4 zero = {0.f, 0.f, 0.f, 0.f};
  f32x4 acc[4][4];
#pragma unroll
  for (int mi = 0; mi < 4; ++mi)
#pragma unroll
    for (int ni = 0; ni < 4; ++ni) acc[mi][ni] = zero;

  int nkt = KE >> 6;
  for (int kt = 0; kt < nkt; ++kt) {
    int ko = kt * 64;
#pragma unroll
    for (int i = 0; i < 4; ++i) {
      async_cp16(aP[i] + ko, smA + (i * 256 + tid) * 16);
      async_cp16(bP[i] + ko, smB + (i * 256 + tid) * 16);
    }
    asm volatile("s_waitcnt vmcnt(0)" ::: "memory");
    __syncthreads();
#pragma unroll
    for (int s = 0; s < 2; ++s) {
      bf16x8 af[4], bfr[4];
#pragma unroll
      for (int mi = 0; mi < 4; ++mi) {
        int row = wm * 64 + mi * 16 + lm;
        af[mi] = *(const bf16x8*)(smA + row * 128 + (((s * 4 + q) ^ (lm & 7)) * 16));
      }
#pragma unroll
      for (int ni = 0; ni < 4; ++ni) {
        int row = wn * 64 + ni * 16 + lm;
        bfr[ni] = *(const bf16x8*)(smB + row * 128 + (((s * 4 + q) ^ (lm & 7)) * 16));
      }
#pragma unroll
      for (int mi = 0; mi < 4; ++mi)
#pragma unroll
        for (int ni = 0; ni < 4; ++ni)
          acc[mi][ni] = __builtin_amdgcn_mfma_f32_16x16x32_bf16(af[mi], bfr[ni], acc[mi][ni], 0, 0, 0);
    }
    __syncthreads();
  }

  // epilogue: C/D layout col=lane&15, row=quad*4+reg (m89-verified)
#pragma unroll
  for (int mi = 0; mi < 4; ++mi) {
#pragma unroll
    for (int ni = 0; ni < 4; ++ni) {
      int col = n0 + wn * 64 + ni * 16 + lm;
#pragma unroll
      for (int r = 0; r < 4; ++r) {
        int row = m0 + wm * 64 + mi * 16 + q * 4 + r;
        C[((size_t)e * CAP + row) * Cstride + col] = f2bf(acc[mi][ni][r]);
      }
    }
  }
}

// ---------------- SiLU(gate)*up, in-place into gate half of h ----------------
struct alignas(16) us8 { u16 v[8]; };
__global__ void act_kernel(u16* __restrict__ h, const int* __restrict__ counts) {
  int e = blockIdx.y;
  int c = blockIdx.x;
  if (c >= counts[e]) return;
  int tid = threadIdx.x;
  if (tid >= ID / 8) return;
  u16* rowp = h + ((size_t)e * CAP + c) * (2 * ID);
  us8 g = *(const us8*)(rowp + tid * 8);
  us8 u = *(const us8*)(rowp + ID + tid * 8);
  us8 o;
#pragma unroll
  for (int j = 0; j < 8; ++j) {
    float gf = bf2f(g.v[j]);
    float uf = bf2f(u.v[j]);
    float a = gf / (1.f + __expf(-gf)) * uf;
    o.v[j] = f2bf(a);
  }
  *(us8*)(rowp + tid * 8) = o;
}

// ---------------- per-token weighted combine (fully overwrites out) ----------------
__global__ void combine_kernel(const float* __restrict__ tw, const int* __restrict__ ids,
                               const int* __restrict__ flatpos, const u16* __restrict__ y,
                               float* __restrict__ out) {
  int t = blockIdx.x;
  int tid = threadIdx.x;
  int h0 = tid * 4;
  float a0 = 0.f, a1 = 0.f, a2 = 0.f, a3 = 0.f;
#pragma unroll
  for (int k = 0; k < 2; ++k) {
    int f = t * 2 + k;
    int p = flatpos[f];
    if (p >= 0) {
      int e = ids[f];
      float w = tw[f];
      const u16* yr = y + ((size_t)e * CAP + p) * HD + h0;
      ushort4 v = *(const ushort4*)yr;
      a0 += w * bf2f(v.x);
      a1 += w * bf2f(v.y);
      a2 += w * bf2f(v.z);
      a3 += w * bf2f(v.w);
    }
  }
  float4 o = {a0, a1, a2, a3};
  *(float4*)(out + (size_t)t * HD + h0) = o;
}

extern "C" void kernel_launch(void* const* d_in, const int* in_sizes, int n_in,
                              void* d_out, int out_size, void* d_ws, size_t ws_size,
                              hipStream_t stream) {
  const float* hidden = (const float*)d_in[0];
  const float* w1 = (const float*)d_in[1];
  const float* w2 = (const float*)d_in[2];
  const float* tw = (const float*)d_in[3];
  const int* ids = (const int*)d_in[4];
  float* out = (float*)d_out;

  char* p = (char*)d_ws;
  auto alloc = [&](size_t b) { char* r = p; p += (b + 255) & ~(size_t)255; return r; };
  u16* bw1 = (u16*)alloc((size_t)NE * 2 * ID * HD * 2);   // 46.1 MB
  u16* bw2 = (u16*)alloc((size_t)NE * HD * ID * 2);        // 23.1 MB
  u16* bx = (u16*)alloc((size_t)TT * HD * 2);              // 4.2 MB
  u16* hbuf = (u16*)alloc((size_t)NE * CAP * 2 * ID * 2);  // 46.1 MB
  u16* ybuf = (u16*)alloc((size_t)NE * CAP * HD * 2);      // 16.8 MB
  int* rowmap = (int*)alloc((size_t)NE * CAP * 4);
  int* flatpos = (int*)alloc((size_t)TT * 2 * 4);
  int* counts = (int*)alloc((size_t)NE * 4);

  int n4w1 = NE * 2 * ID * HD / 4;
  cvt_kernel<<<(n4w1 + 255) / 256, 256, 0, stream>>>((const float4*)w1, (ushort4*)bw1, n4w1);
  int n4w2 = NE * HD * ID / 4;
  cvt_kernel<<<(n4w2 + 255) / 256, 256, 0, stream>>>((const float4*)w2, (ushort4*)bw2, n4w2);
  int n4x = TT * HD / 4;
  cvt_kernel<<<(n4x + 255) / 256, 256, 0, stream>>>((const float4*)hidden, (ushort4*)bx, n4x);

  route_kernel<<<1, 256, 0, stream>>>(ids, rowmap, flatpos, counts);

  // GEMM1: h[e, c, 0:2816] = x_gathered[c, :1024] . w1[e, n, :1024]^T
  gemm_bt<true><<<dim3(2 * ID / 128, CAP / 128, NE), 256, 0, stream>>>(
      bx, bw1, hbuf, rowmap, counts, HD, HD, (long long)2 * ID * HD, 2 * ID);

  act_kernel<<<dim3(CAP, NE), 256, 0, stream>>>(hbuf, counts);

  // GEMM2: y[e, c, 0:1024] = act[c, :1408] . w2[e, n, :1408]^T  (act = gate half of hbuf, stride 2816)
  gemm_bt<false><<<dim3(HD / 128, CAP / 128, NE), 256, 0, stream>>>(
      hbuf, bw2, ybuf, rowmap, counts, ID, 2 * ID, (long long)HD * ID, HD);

  combine_kernel<<<TT, 256, 0, stream>>>(tw, ids, flatpos, ybuf, out);
}

// Round 2
// 289.206 us; speedup vs baseline: 1.0018x; 1.0018x over previous
//
#include <hip/hip_runtime.h>

#define NE 8
#define CAP 1024
#define HD 1024
#define ID 1408
#define TT 2048

typedef __attribute__((ext_vector_type(8))) short bf16x8;
typedef __attribute__((ext_vector_type(4))) float f32x4;
typedef unsigned short u16;
typedef unsigned int u32;
typedef unsigned long long u64;

__device__ __forceinline__ u16 f2bf(float f) {
  u32 u = __float_as_uint(f);
  u = (u + 0x7fffu + ((u >> 16) & 1u)) >> 16;
  return (u16)u;
}
__device__ __forceinline__ float bf2f(u16 b) {
  return __uint_as_float(((u32)b) << 16);
}

__device__ __forceinline__ void async_cp16(const void* g, void* l) {
  __builtin_amdgcn_global_load_lds(
      (const __attribute__((address_space(1))) u32*)g,
      (__attribute__((address_space(3))) u32*)l, 16, 0, 0);
}

// ---------------- fp32 -> bf16 convert ----------------
__global__ void cvt_kernel(const float4* __restrict__ src, ushort4* __restrict__ dst, int n4) {
  int i = blockIdx.x * 256 + threadIdx.x;
  if (i >= n4) return;
  float4 v = src[i];
  ushort4 o;
  o.x = f2bf(v.x); o.y = f2bf(v.y); o.z = f2bf(v.z); o.w = f2bf(v.w);
  dst[i] = o;
}

// ---------------- routing: exact flat-order cumsum positions ----------------
// Parallel version: per-thread counts (packed 8x8bit), Hillis-Steele scan
// over 256 threads for all 8 experts at once, then per-thread serial assign.
__global__ void route_kernel(const int* __restrict__ ids, int* __restrict__ rowmap,
                             int* __restrict__ flatpos, int* __restrict__ counts) {
  __shared__ int ids_s[TT * 2];
  __shared__ int sc[256][NE + 1];  // +1 pad: stride 9 breaks 8-stride bank conflicts
  int tid = threadIdx.x;
  for (int i = tid; i < TT * 2; i += 256) ids_s[i] = ids[i];
  __syncthreads();
  int base = tid * 16;
  u64 own64 = 0;  // 8 packed 8-bit counters (max 16 each)
#pragma unroll
  for (int j = 0; j < 16; ++j) own64 += 1ull << (ids_s[base + j] * 8);
  int own[NE];
#pragma unroll
  for (int e = 0; e < NE; ++e) { own[e] = (int)((own64 >> (e * 8)) & 0xff); sc[tid][e] = own[e]; }
  __syncthreads();
  // inclusive scan along tid for each expert
  for (int off = 1; off < 256; off <<= 1) {
    int v[NE];
    if (tid >= off) {
#pragma unroll
      for (int e = 0; e < NE; ++e) v[e] = sc[tid - off][e];
    }
    __syncthreads();
    if (tid >= off) {
#pragma unroll
      for (int e = 0; e < NE; ++e) sc[tid][e] += v[e];
    }
    __syncthreads();
  }
  if (tid == 255) {
#pragma unroll
    for (int e = 0; e < NE; ++e) counts[e] = sc[255][e] < CAP ? sc[255][e] : CAP;
  }
  // exclusive base per thread
  int excl[NE];
#pragma unroll
  for (int e = 0; e < NE; ++e) excl[e] = sc[tid][e] - own[e];
  __syncthreads();
#pragma unroll
  for (int e = 0; e < NE; ++e) sc[tid][e] = excl[e];
  // each thread only touches its own row below; no barrier needed
#pragma unroll
  for (int j = 0; j < 16; ++j) {
    int f = base + j;
    int e = ids_s[f];
    int p = sc[tid][e]++;
    if (p < CAP) { rowmap[e * CAP + p] = f; flatpos[f] = p; }
    else flatpos[f] = -1;
  }
}

// ---------------- bf16 BT GEMM: C[m,n] = sum_k A[m,k]*B[n,k] ----------------
// m97 structure: 128x128 tile, BK=64, 4 waves (2x2 of 64x64), 16x16x32 MFMA,
// global_load_lds width=16, XOR chunk swizzle.
// XCD swizzle: grid = (E, Mblocks, Nblocks); with gridDim.x == 8, linear block
// id % 8 == blockIdx.x == expert -> each XCD owns one expert; within an XCD
// m-blocks dispatch fastest, so blocks sharing a B-tile run back-to-back and
// B re-reads hit that XCD's L2.
template <bool GATHER>
__global__ __launch_bounds__(256) void gemm_bt(
    const u16* __restrict__ A, const u16* __restrict__ B, u16* __restrict__ C,
    const int* __restrict__ rowmap, const int* __restrict__ counts,
    int KE, int Astride, long long Bexp, int Cstride) {
  int e = blockIdx.x;
  int count = counts[e];
  int m0 = blockIdx.y * 128;
  if (m0 >= count) return;
  int n0 = blockIdx.z * 128;
  int tid = threadIdx.x;
  int lane = tid & 63, wid = tid >> 6;
  int wm = wid >> 1, wn = wid & 1;
  int q = lane >> 4, lm = lane & 15;

  __shared__ __align__(16) char smA[128 * 128];
  __shared__ __align__(16) char smB[128 * 128];

  int rloc = tid >> 3;
  int chs = ((tid & 7) ^ (rloc & 7)) * 8;  // swizzled element offset within 64-elem k-tile
  const u16* aP[4];
  const u16* bP[4];
#pragma unroll
  for (int i = 0; i < 4; ++i) {
    int row = rloc + 32 * i;
    if (GATHER) {
      int gr = m0 + row;
      int f = (gr < count) ? rowmap[e * CAP + gr] : 0;
      aP[i] = A + (size_t)(f >> 1) * Astride + chs;  // token = f/2 (K_top=2)
    } else {
      aP[i] = A + ((size_t)e * CAP + m0 + row) * Astride + chs;
    }
    bP[i] = B + (size_t)e * Bexp + (size_t)(n0 + row) * KE + chs;
  }

  f32x4 zero = {0.f, 0.f, 0.f, 0.f};
  f32x4 acc[4][4];
#pragma unroll
  for (int mi = 0; mi < 4; ++mi)
#pragma unroll
    for (int ni = 0; ni < 4; ++ni) acc[mi][ni] = zero;

  int nkt = KE >> 6;
  for (int kt = 0; kt < nkt; ++kt) {
    int ko = kt * 64;
#pragma unroll
    for (int i = 0; i < 4; ++i) {
      async_cp16(aP[i] + ko, smA + (i * 256 + tid) * 16);
      async_cp16(bP[i] + ko, smB + (i * 256 + tid) * 16);
    }
    asm volatile("s_waitcnt vmcnt(0)" ::: "memory");
    __syncthreads();
#pragma unroll
    for (int s = 0; s < 2; ++s) {
      bf16x8 af[4], bfr[4];
#pragma unroll
      for (int mi = 0; mi < 4; ++mi) {
        int row = wm * 64 + mi * 16 + lm;
        af[mi] = *(const bf16x8*)(smA + row * 128 + (((s * 4 + q) ^ (lm & 7)) * 16));
      }
#pragma unroll
      for (int ni = 0; ni < 4; ++ni) {
        int row = wn * 64 + ni * 16 + lm;
        bfr[ni] = *(const bf16x8*)(smB + row * 128 + (((s * 4 + q) ^ (lm & 7)) * 16));
      }
#pragma unroll
      for (int mi = 0; mi < 4; ++mi)
#pragma unroll
        for (int ni = 0; ni < 4; ++ni)
          acc[mi][ni] = __builtin_amdgcn_mfma_f32_16x16x32_bf16(af[mi], bfr[ni], acc[mi][ni], 0, 0, 0);
    }
    __syncthreads();
  }

  // epilogue: C/D layout col=lane&15, row=quad*4+reg (m89-verified)
#pragma unroll
  for (int mi = 0; mi < 4; ++mi) {
#pragma unroll
    for (int ni = 0; ni < 4; ++ni) {
      int col = n0 + wn * 64 + ni * 16 + lm;
#pragma unroll
      for (int r = 0; r < 4; ++r) {
        int row = m0 + wm * 64 + mi * 16 + q * 4 + r;
        C[((size_t)e * CAP + row) * Cstride + col] = f2bf(acc[mi][ni][r]);
      }
    }
  }
}

// ---------------- SiLU(gate)*up, in-place into gate half of h ----------------
struct alignas(16) us8 { u16 v[8]; };
__global__ void act_kernel(u16* __restrict__ h, const int* __restrict__ counts) {
  int e = blockIdx.y;
  int c = blockIdx.x;
  if (c >= counts[e]) return;
  int tid = threadIdx.x;
  if (tid >= ID / 8) return;
  u16* rowp = h + ((size_t)e * CAP + c) * (2 * ID);
  us8 g = *(const us8*)(rowp + tid * 8);
  us8 u = *(const us8*)(rowp + ID + tid * 8);
  us8 o;
#pragma unroll
  for (int j = 0; j < 8; ++j) {
    float gf = bf2f(g.v[j]);
    float uf = bf2f(u.v[j]);
    float a = gf / (1.f + __expf(-gf)) * uf;
    o.v[j] = f2bf(a);
  }
  *(us8*)(rowp + tid * 8) = o;
}

// ---------------- per-token weighted combine (fully overwrites out) ----------------
__global__ void combine_kernel(const float* __restrict__ tw, const int* __restrict__ ids,
                               const int* __restrict__ flatpos, const u16* __restrict__ y,
                               float* __restrict__ out) {
  int t = blockIdx.x;
  int tid = threadIdx.x;
  int h0 = tid * 4;
  float a0 = 0.f, a1 = 0.f, a2 = 0.f, a3 = 0.f;
#pragma unroll
  for (int k = 0; k < 2; ++k) {
    int f = t * 2 + k;
    int p = flatpos[f];
    if (p >= 0) {
      int e = ids[f];
      float w = tw[f];
      const u16* yr = y + ((size_t)e * CAP + p) * HD + h0;
      ushort4 v = *(const ushort4*)yr;
      a0 += w * bf2f(v.x);
      a1 += w * bf2f(v.y);
      a2 += w * bf2f(v.z);
      a3 += w * bf2f(v.w);
    }
  }
  float4 o = {a0, a1, a2, a3};
  *(float4*)(out + (size_t)t * HD + h0) = o;
}

extern "C" void kernel_launch(void* const* d_in, const int* in_sizes, int n_in,
                              void* d_out, int out_size, void* d_ws, size_t ws_size,
                              hipStream_t stream) {
  const float* hidden = (const float*)d_in[0];
  const float* w1 = (const float*)d_in[1];
  const float* w2 = (const float*)d_in[2];
  const float* tw = (const float*)d_in[3];
  const int* ids = (const int*)d_in[4];
  float* out = (float*)d_out;

  char* p = (char*)d_ws;
  auto alloc = [&](size_t b) { char* r = p; p += (b + 255) & ~(size_t)255; return r; };
  u16* bw1 = (u16*)alloc((size_t)NE * 2 * ID * HD * 2);   // 46.1 MB
  u16* bw2 = (u16*)alloc((size_t)NE * HD * ID * 2);        // 23.1 MB
  u16* bx = (u16*)alloc((size_t)TT * HD * 2);              // 4.2 MB
  u16* hbuf = (u16*)alloc((size_t)NE * CAP * 2 * ID * 2);  // 46.1 MB
  u16* ybuf = (u16*)alloc((size_t)NE * CAP * HD * 2);      // 16.8 MB
  int* rowmap = (int*)alloc((size_t)NE * CAP * 4);
  int* flatpos = (int*)alloc((size_t)TT * 2 * 4);
  int* counts = (int*)alloc((size_t)NE * 4);

  int n4w1 = NE * 2 * ID * HD / 4;
  cvt_kernel<<<(n4w1 + 255) / 256, 256, 0, stream>>>((const float4*)w1, (ushort4*)bw1, n4w1);
  int n4w2 = NE * HD * ID / 4;
  cvt_kernel<<<(n4w2 + 255) / 256, 256, 0, stream>>>((const float4*)w2, (ushort4*)bw2, n4w2);
  int n4x = TT * HD / 4;
  cvt_kernel<<<(n4x + 255) / 256, 256, 0, stream>>>((const float4*)hidden, (ushort4*)bx, n4x);

  route_kernel<<<1, 256, 0, stream>>>(ids, rowmap, flatpos, counts);

  // GEMM1: h[e, c, 0:2816] = x_gathered[c, :1024] . w1[e, n, :1024]^T
  gemm_bt<true><<<dim3(NE, CAP / 128, 2 * ID / 128), 256, 0, stream>>>(
      bx, bw1, hbuf, rowmap, counts, HD, HD, (long long)2 * ID * HD, 2 * ID);

  act_kernel<<<dim3(CAP, NE), 256, 0, stream>>>(hbuf, counts);

  // GEMM2: y[e, c, 0:1024] = act[c, :1408] . w2[e, n, :1408]^T  (act = gate half of hbuf, stride 2816)
  gemm_bt<false><<<dim3(NE, CAP / 128, HD / 128), 256, 0, stream>>>(
      hbuf, bw2, ybuf, rowmap, counts, ID, 2 * ID, (long long)HD * ID, HD);

  combine_kernel<<<TT, 256, 0, stream>>>(tw, ids, flatpos, ybuf, out);
}